// Round 1
// baseline (396.093 us; speedup 1.0000x reference)
//
#include <hip/hip_runtime.h>
#include <math.h>

// Problem constants (from reference setup_inputs)
#define BB 64
#define MM 50
#define PP 24564
#define CC 2
#define NBLK ((PP + 255) / 256)   // 96 blocks of 256 over priors
#define THRESH 0.2f

// ---------------- kernel 0: priors cxcy -> xy + area ----------------
__global__ void k_priors(const float4* __restrict__ pr_cxcy,
                         float4* __restrict__ pr_xy,
                         float* __restrict__ parea) {
    int p = blockIdx.x * 256 + threadIdx.x;
    if (p >= PP) return;
    float4 c = pr_cxcy[p];
    float4 xy;
    xy.x = c.x - c.z * 0.5f;
    xy.y = c.y - c.w * 0.5f;
    xy.z = c.x + c.z * 0.5f;
    xy.w = c.y + c.w * 0.5f;
    pr_xy[p] = xy;
    parea[p] = (xy.z - xy.x) * (xy.w - xy.y);
}

__device__ __forceinline__ float iou_fn(float4 a, float area_a, float4 b, float area_b) {
    float lx = fmaxf(a.x, b.x), ly = fmaxf(a.y, b.y);
    float rx = fminf(a.z, b.z), ry = fminf(a.w, b.w);
    float iw = fmaxf(rx - lx, 0.0f), ih = fmaxf(ry - ly, 0.0f);
    float inter = iw * ih;
    return inter / (area_a + area_b - inter);
}

// ---------------- kernel A: per-prior best object (max/argmax over M) ----------------
__global__ void k_best_per_prior(const float4* __restrict__ pr_xy,
                                 const float* __restrict__ parea,
                                 const float4* __restrict__ boxes,
                                 float* __restrict__ ovbest,
                                 int* __restrict__ objbest) {
    int b = blockIdx.y;
    int p = blockIdx.x * 256 + threadIdx.x;
    __shared__ float4 sbox[MM];
    __shared__ float sarea[MM];
    if (threadIdx.x < MM) {
        float4 bx = boxes[b * MM + threadIdx.x];
        sbox[threadIdx.x] = bx;
        sarea[threadIdx.x] = (bx.z - bx.x) * (bx.w - bx.y);
    }
    __syncthreads();
    if (p >= PP) return;
    float4 pxy = pr_xy[p];
    float pa = parea[p];
    float best = -1.0f;
    int bm = 0;
    for (int m = 0; m < MM; ++m) {
        float iou = iou_fn(sbox[m], sarea[m], pxy, pa);
        if (iou > best) { best = iou; bm = m; }   // strict > : first occurrence wins
    }
    ovbest[(size_t)b * PP + p] = best;
    objbest[(size_t)b * PP + p] = bm;
}

// ---------------- kernel B: per-object best prior (argmax over P) ----------------
__global__ void k_best_per_object(const float4* __restrict__ pr_xy,
                                  const float* __restrict__ parea,
                                  const float4* __restrict__ boxes,
                                  int* __restrict__ pfeo) {
    int m = blockIdx.x, b = blockIdx.y;
    float4 bx = boxes[b * MM + m];
    float ba = (bx.z - bx.x) * (bx.w - bx.y);
    unsigned long long bestkey = 0ull;
    for (int p = threadIdx.x; p < PP; p += 256) {
        float iou = iou_fn(bx, ba, pr_xy[p], parea[p]);
        // iou >= 0 -> float bits monotone as u32; tie -> larger ~p = smaller p wins
        unsigned long long key =
            ((unsigned long long)__float_as_uint(iou) << 32) | (unsigned int)(~p);
        if (key > bestkey) bestkey = key;
    }
    __shared__ unsigned long long sk[256];
    sk[threadIdx.x] = bestkey;
    __syncthreads();
    for (int s = 128; s > 0; s >>= 1) {
        if (threadIdx.x < s) {
            unsigned long long o = sk[threadIdx.x + s];
            if (o > sk[threadIdx.x]) sk[threadIdx.x] = o;
        }
        __syncthreads();
    }
    if (threadIdx.x == 0) pfeo[b * MM + m] = (int)(~(unsigned int)sk[0]);
}

// ---------------- kernel C: force-assign (sequential per image) ----------------
__global__ void k_force(const int* __restrict__ pfeo,
                        float* __restrict__ ovbest,
                        int* __restrict__ objbest) {
    int b = threadIdx.x;
    if (b >= BB) return;
    for (int m = 0; m < MM; ++m) {          // ascending m: last-wins on duplicates
        int p = pfeo[b * MM + m];
        objbest[(size_t)b * PP + p] = m;
        ovbest[(size_t)b * PP + p] = 1.0f;
    }
}

// ---------------- kernel D: per-prior loss terms + partials ----------------
__global__ void k_perprior(const float* __restrict__ ovbest,
                           const int* __restrict__ objbest,
                           const float4* __restrict__ boxes,
                           const float4* __restrict__ pr_cxcy,
                           const float4* __restrict__ plocs,
                           const float2* __restrict__ scores,
                           float* __restrict__ confneg,
                           int* __restrict__ npos_part,
                           float* __restrict__ cpos_part,
                           float* __restrict__ loc_part) {
    int b = blockIdx.y;
    int p = blockIdx.x * 256 + threadIdx.x;
    int np = 0;
    float cpos = 0.0f, lloc = 0.0f;
    if (p < PP) {
        size_t idx = (size_t)b * PP + p;
        float ov = ovbest[idx];
        bool pos = (ov >= THRESH);
        float2 sc = scores[idx];
        float mx = fmaxf(sc.x, sc.y);
        float lse = mx + logf(expf(sc.x - mx) + expf(sc.y - mx));
        float conf = pos ? (lse - sc.y) : (lse - sc.x);   // -logp[label]
        confneg[idx] = pos ? 0.0f : conf;
        if (pos) {
            np = 1;
            cpos = conf;
            int obj = objbest[idx];
            float4 bx = boxes[b * MM + obj];
            float cx = (bx.x + bx.z) * 0.5f, cy = (bx.y + bx.w) * 0.5f;
            float w = bx.z - bx.x, h = bx.w - bx.y;
            float4 pc = pr_cxcy[p];
            float g0 = (cx - pc.x) / (pc.z * 0.1f);
            float g1 = (cy - pc.y) / (pc.w * 0.1f);
            float g2 = logf(w / pc.z) * 5.0f;
            float g3 = logf(h / pc.w) * 5.0f;
            float4 pl = plocs[idx];
            lloc = fabsf(pl.x - g0) + fabsf(pl.y - g1) +
                   fabsf(pl.z - g2) + fabsf(pl.w - g3);
        }
    }
    __shared__ int si[256];
    __shared__ float s1[256], s2[256];
    si[threadIdx.x] = np; s1[threadIdx.x] = cpos; s2[threadIdx.x] = lloc;
    __syncthreads();
    for (int s = 128; s > 0; s >>= 1) {
        if (threadIdx.x < s) {
            si[threadIdx.x] += si[threadIdx.x + s];
            s1[threadIdx.x] += s1[threadIdx.x + s];
            s2[threadIdx.x] += s2[threadIdx.x + s];
        }
        __syncthreads();
    }
    if (threadIdx.x == 0) {
        int o = b * NBLK + blockIdx.x;
        npos_part[o] = si[0];
        cpos_part[o] = s1[0];
        loc_part[o] = s2[0];
    }
}

// ---------------- kernel E: per-image top-K sum of conf_neg ----------------
__global__ void k_topk(const float* __restrict__ confneg,
                       const int* __restrict__ npos_part,
                       float* __restrict__ chard) {
    int b = blockIdx.x;
    __shared__ int scnt[256];
    // reduce this image's n_pos partials
    int v = (threadIdx.x < NBLK) ? npos_part[b * NBLK + threadIdx.x] : 0;
    scnt[threadIdx.x] = v;
    __syncthreads();
    for (int s = 128; s > 0; s >>= 1) {
        if (threadIdx.x < s) scnt[threadIdx.x] += scnt[threadIdx.x + s];
        __syncthreads();
    }
    int npos = scnt[0];
    __syncthreads();
    long long Kl = 3LL * npos;
    int K = (Kl > PP) ? PP : (int)Kl;
    if (K == 0) {
        if (threadIdx.x == 0) chard[b] = 0.0f;
        return;
    }
    const unsigned int* keys = (const unsigned int*)(confneg + (size_t)b * PP);
    unsigned int prefix = 0;
    for (int bit = 30; bit >= 0; --bit) {      // values >= 0 -> bit31 never set
        unsigned int test = prefix | (1u << bit);
        int cnt = 0;
        for (int p = threadIdx.x; p < PP; p += 256) cnt += (keys[p] >= test) ? 1 : 0;
        scnt[threadIdx.x] = cnt;
        __syncthreads();
        for (int s = 128; s > 0; s >>= 1) {
            if (threadIdx.x < s) scnt[threadIdx.x] += scnt[threadIdx.x + s];
            __syncthreads();
        }
        if (scnt[0] >= K) prefix = test;       // uniform across threads
        __syncthreads();
    }
    // prefix == K-th largest key. Sum strictly-greater + ties at the cut.
    float ssum = 0.0f;
    int cg = 0;
    for (int p = threadIdx.x; p < PP; p += 256) {
        unsigned int k = keys[p];
        if (k > prefix) { ssum += __uint_as_float(k); cg++; }
    }
    __shared__ float sfs[256];
    scnt[threadIdx.x] = cg; sfs[threadIdx.x] = ssum;
    __syncthreads();
    for (int s = 128; s > 0; s >>= 1) {
        if (threadIdx.x < s) {
            scnt[threadIdx.x] += scnt[threadIdx.x + s];
            sfs[threadIdx.x] += sfs[threadIdx.x + s];
        }
        __syncthreads();
    }
    if (threadIdx.x == 0)
        chard[b] = sfs[0] + (float)(K - scnt[0]) * __uint_as_float(prefix);
}

// ---------------- kernel F: final deterministic combine ----------------
__global__ void k_final(const int* __restrict__ npos_part,
                        const float* __restrict__ cpos_part,
                        const float* __restrict__ loc_part,
                        const float* __restrict__ chard,
                        float* __restrict__ out) {
    __shared__ int si[256];
    __shared__ float s1[256], s2[256], s3[256];
    int tn = 0; float tc = 0.0f, tl = 0.0f;
    for (int i = threadIdx.x; i < BB * NBLK; i += 256) {
        tn += npos_part[i];
        tc += cpos_part[i];
        tl += loc_part[i];
    }
    float th = (threadIdx.x < BB) ? chard[threadIdx.x] : 0.0f;
    si[threadIdx.x] = tn; s1[threadIdx.x] = tc; s2[threadIdx.x] = tl; s3[threadIdx.x] = th;
    __syncthreads();
    for (int s = 128; s > 0; s >>= 1) {
        if (threadIdx.x < s) {
            si[threadIdx.x] += si[threadIdx.x + s];
            s1[threadIdx.x] += s1[threadIdx.x + s];
            s2[threadIdx.x] += s2[threadIdx.x + s];
            s3[threadIdx.x] += s3[threadIdx.x + s];
        }
        __syncthreads();
    }
    if (threadIdx.x == 0) {
        float tp = (float)si[0];
        out[0] = (s3[0] + s1[0]) / tp + s2[0] / (tp * 4.0f);
    }
}

extern "C" void kernel_launch(void* const* d_in, const int* in_sizes, int n_in,
                              void* d_out, int out_size, void* d_ws, size_t ws_size,
                              hipStream_t stream) {
    const float4* plocs   = (const float4*)d_in[0];   // (B,P,4)
    const float2* scores  = (const float2*)d_in[1];   // (B,P,2)
    const float4* boxes   = (const float4*)d_in[2];   // (B,M,4)
    const float4* priors  = (const float4*)d_in[3];   // (P,4) cxcywh
    float* out = (float*)d_out;

    char* ws = (char*)d_ws;
    size_t off = 0;
    auto alloc = [&](size_t bytes) -> void* {
        void* p = ws + off;
        off += (bytes + 255) & ~(size_t)255;
        return p;
    };
    float4* pr_xy    = (float4*)alloc((size_t)PP * 16);
    float*  parea    = (float*) alloc((size_t)PP * 4);
    float*  ovbest   = (float*) alloc((size_t)BB * PP * 4);
    int*    objbest  = (int*)   alloc((size_t)BB * PP * 4);
    int*    pfeo     = (int*)   alloc((size_t)BB * MM * 4);
    float*  confneg  = (float*) alloc((size_t)BB * PP * 4);
    int*    npos_p   = (int*)   alloc((size_t)BB * NBLK * 4);
    float*  cpos_p   = (float*) alloc((size_t)BB * NBLK * 4);
    float*  loc_p    = (float*) alloc((size_t)BB * NBLK * 4);
    float*  chard    = (float*) alloc((size_t)BB * 4);
    (void)ws_size; (void)in_sizes; (void)n_in; (void)out_size;

    k_priors<<<dim3(NBLK), 256, 0, stream>>>(priors, pr_xy, parea);
    k_best_per_prior<<<dim3(NBLK, BB), 256, 0, stream>>>(pr_xy, parea, boxes, ovbest, objbest);
    k_best_per_object<<<dim3(MM, BB), 256, 0, stream>>>(pr_xy, parea, boxes, pfeo);
    k_force<<<1, 64, 0, stream>>>(pfeo, ovbest, objbest);
    k_perprior<<<dim3(NBLK, BB), 256, 0, stream>>>(ovbest, objbest, boxes, priors,
                                                   plocs, scores, confneg,
                                                   npos_p, cpos_p, loc_p);
    k_topk<<<BB, 256, 0, stream>>>(confneg, npos_p, chard);
    k_final<<<1, 256, 0, stream>>>(npos_p, cpos_p, loc_p, chard, out);
}